// Round 16
// baseline (207.827 us; speedup 1.0000x reference)
//
#include <hip/hip_runtime.h>
#include <math.h>

#define BIMG 8
#define HW 9216
#define CENC 512
#define NN 128
#define DD 256
#define NHEAD 8
#define DH 32
#define ROWS1 1024
#define ROWS2 2048
#define TAILB 520   // 8 sinkhorn + 512 cls blocks

typedef unsigned long long ull;
typedef unsigned short u16;
typedef __attribute__((ext_vector_type(4))) float f32x4;
typedef __attribute__((ext_vector_type(4))) unsigned u32x4;
typedef __attribute__((ext_vector_type(2))) unsigned u32x2;

__device__ __forceinline__ u16 f2bf(float f) {
  unsigned u = __float_as_uint(f);
  u += 0x7fffu + ((u >> 16) & 1u);
  return (u16)(u >> 16);
}
__device__ __forceinline__ float bf2f(unsigned h) { return __uint_as_float(h << 16); }
__device__ __forceinline__ unsigned pack2(float a, float b) {
  return (unsigned)f2bf(a) | ((unsigned)f2bf(b) << 16);
}
__device__ __forceinline__ void mfma_b(f32x4& acc, u32x4 a, u32x4 b) {
  asm volatile("v_mfma_f32_16x16x32_bf16 %0, %1, %2, %0" : "+v"(acc) : "v"(a), "v"(b));
}
// safe variant: s_nop covers VALU-write -> MFMA-read hazard (invisible to compiler in asm)
__device__ __forceinline__ void mfma_s(f32x4& acc, u32x4 a, u32x4 b) {
  asm volatile("s_nop 1\n\tv_mfma_f32_16x16x32_bf16 %0, %1, %2, %0" : "+v"(acc) : "v"(a), "v"(b));
}

__device__ __forceinline__ ull cmpex_keep(ull k, ull o, bool keepMax) {
  return ((k > o) == keepMax) ? k : o;
}
__device__ __forceinline__ void bsort64(ull& k, int lane) {
#pragma unroll
  for (int size = 2; size <= 64; size <<= 1) {
#pragma unroll
    for (int stride = size >> 1; stride > 0; stride >>= 1) {
      ull o = __shfl_xor(k, stride);
      bool keepMax = (((lane & size) == 0) == ((lane & stride) == 0));
      k = cmpex_keep(k, o, keepMax);
    }
  }
}
__device__ __forceinline__ void bmerge64(ull& top, ull b, int lane) {
  ull rev = __shfl_xor(b, 63);
  ull m = top > rev ? top : rev;
#pragma unroll
  for (int stride = 32; stride > 0; stride >>= 1) {
    ull o = __shfl_xor(m, stride);
    m = cmpex_keep(m, o, (lane & stride) == 0);
  }
  top = m;
}
__device__ __forceinline__ ull lds_merge(ull a, ull brev, int lane) {
  ull m = a > brev ? a : brev;
#pragma unroll
  for (int stride = 32; stride > 0; stride >>= 1) {
    ull o = __shfl_xor(m, stride);
    m = cmpex_keep(m, o, (lane & stride) == 0);
  }
  return m;
}

// ---- launch 1 (512 thr): 0..31 top-64 ; 32..799 W transpose ; 800..831 cls_W1 ;
//                          832..1023 fused cross weights ----
__global__ __launch_bounds__(512) void head_kernel(const float* __restrict__ score_s,
                                                   const float* __restrict__ score_t,
                                                   int* __restrict__ idx_out,
                                                   float* __restrict__ loss_acc,
                                                   const float* __restrict__ hw1,
                                                   const float* __restrict__ hw2,
                                                   const float* __restrict__ iw,
                                                   const float* __restrict__ cw,
                                                   const float* __restrict__ aw,
                                                   const float* __restrict__ clsW1,
                                                   const float* __restrict__ intra_b,
                                                   const float* __restrict__ cross_b,
                                                   u16* __restrict__ wt,
                                                   u16* __restrict__ w1t,
                                                   u16* __restrict__ wt_f,
                                                   float* __restrict__ bfq) {
  __shared__ union {
    struct { ull sm[512]; float tile[32][33]; } a;
    struct { float Wo[32][264]; float Wc[256][40]; } b;
  } HS;
  int tid = threadIdx.x;
  if (blockIdx.x < 32) {
    int blk = blockIdx.x;
    int bi = blk >> 1, neg = blk & 1;
    int lane = tid & 63, w = tid >> 6;
    if (blk == 0 && tid < 4) loss_acc[tid] = 0.f;   // loss0, loss1, pad, ticket
    const float* sp = (bi < 8 ? score_s : score_t) + (size_t)(bi & 7) * HW;
    int q0 = w * 18;
    ull keys[18];
#pragma unroll
    for (int j = 0; j < 18; ++j) {
      float x = sp[(q0 + j) * 64 + lane];
      unsigned ub = __float_as_uint(x);
      unsigned u = (ub & 0x80000000u) ? ~ub : (ub | 0x80000000u);
      if (neg) u = ~u;
      int gi = (q0 + j) * 64 + lane;
      keys[j] = ((ull)u << 32) | (unsigned)(~gi);
    }
    ull top1 = keys[0]; bsort64(top1, lane);
    ull top2 = keys[9]; bsort64(top2, lane);
#pragma unroll
    for (int j = 1; j < 9; ++j) {
      ull k1 = keys[j], k2 = keys[9 + j];
      bsort64(k1, lane);
      bsort64(k2, lane);
      bmerge64(top1, k1, lane);
      bmerge64(top2, k2, lane);
    }
    bmerge64(top1, top2, lane);
    HS.a.sm[w * 64 + lane] = top1;
    __syncthreads();
    if (w < 4) {
      ull m = lds_merge(HS.a.sm[(2 * w) * 64 + lane],
                        HS.a.sm[(2 * w + 1) * 64 + (63 - lane)], lane);
      HS.a.sm[(2 * w) * 64 + lane] = m;
    }
    __syncthreads();
    if (w < 2) {
      ull m = lds_merge(HS.a.sm[(4 * w) * 64 + lane],
                        HS.a.sm[(4 * w + 2) * 64 + (63 - lane)], lane);
      HS.a.sm[(4 * w) * 64 + lane] = m;
    }
    __syncthreads();
    if (w == 0) {
      ull m = lds_merge(HS.a.sm[lane], HS.a.sm[4 * 64 + (63 - lane)], lane);
      idx_out[bi * NN + neg * 64 + lane] = (int)(~(unsigned)(m & 0xffffffffull));
    }
  } else if (blockIdx.x < 800) {
    int bid = blockIdx.x - 32;
    const float* src; u16* dst; int K, k0, n0;
    if (bid < 128) {
      src = hw1; dst = wt; K = 512;
      k0 = (bid >> 3) * 32; n0 = (bid & 7) * 32;
    } else {
      int id2 = bid - 128;
      int m = id2 >> 6, tt = id2 & 63;
      K = 256;
      k0 = (tt >> 3) * 32; n0 = (tt & 7) * 32;
      src = (m == 0) ? hw2 : (m < 5) ? iw + (size_t)(m - 1) * 65536
          : (m < 9) ? cw + (size_t)(m - 5) * 65536 : aw;
      dst = wt + 131072 + (size_t)m * 65536;
    }
    int r = tid >> 3, c = (tid & 7) * 4;
    if (tid < 256) {
      float4 v = *(const float4*)&src[(size_t)(k0 + r) * 256 + n0 + c];
      HS.a.tile[r][c] = v.x; HS.a.tile[r][c + 1] = v.y;
      HS.a.tile[r][c + 2] = v.z; HS.a.tile[r][c + 3] = v.w;
    }
    __syncthreads();
    if (tid < 256) {
      u32x2 o;
      o[0] = pack2(HS.a.tile[c][r], HS.a.tile[c + 1][r]);
      o[1] = pack2(HS.a.tile[c + 2][r], HS.a.tile[c + 3][r]);
      *(u32x2*)&dst[(size_t)(n0 + r) * K + k0 + c] = o;
    }
  } else if (blockIdx.x < 832) {
    int bid3 = blockIdx.x - 800;     // cls_W1 [256][128] -> bf16 [128][256]
    int k0 = (bid3 >> 2) * 32, n0 = (bid3 & 3) * 32;
    int r = tid >> 3, c = (tid & 7) * 4;
    if (tid < 256) {
      float4 v = *(const float4*)&clsW1[(size_t)(k0 + r) * 128 + n0 + c];
      HS.a.tile[r][c] = v.x; HS.a.tile[r][c + 1] = v.y;
      HS.a.tile[r][c + 2] = v.z; HS.a.tile[r][c + 3] = v.w;
    }
    __syncthreads();
    if (tid < 256) {
      u32x2 o;
      o[0] = pack2(HS.a.tile[c][r], HS.a.tile[c + 1][r]);
      o[1] = pack2(HS.a.tile[c + 2][r], HS.a.tile[c + 3][r]);
      *(u32x2*)&w1t[(size_t)(n0 + r) * 256 + k0 + c] = o;
    }
  } else {
    // fused cross weights: W'[z](k,n) = sum_j Wo_i[k][j]*Wc[z][j][n] (fp32) -> bf16 [n][k]
    int bid4 = blockIdx.x - 832;       // 0..191
    int z = bid4 >> 6, tt = bid4 & 63;
    int k0 = (tt >> 3) * 32, n0 = (tt & 7) * 32;
    const float* Wo = iw + 3 * 65536;
    const float* Wc = cw + (size_t)z * 65536;
    for (int e = tid; e < 2048; e += 512) {
      int row = e >> 6, c4 = (e & 63) * 4;
      *(float4*)&HS.b.Wo[row][c4] = *(const float4*)&Wo[(size_t)(k0 + row) * 256 + c4];
    }
    for (int e = tid; e < 2048; e += 512) {
      int row = e >> 3, c4 = (e & 7) * 4;
      *(float4*)&HS.b.Wc[row][c4] = *(const float4*)&Wc[(size_t)row * 256 + n0 + c4];
    }
    __syncthreads();
    int k = tid >> 4, half = (tid >> 3) & 1, nb = (tid & 7) * 4;
    float a0 = 0.f, a1 = 0.f, a2 = 0.f, a3 = 0.f;
    int jb = half * 128;
#pragma unroll 8
    for (int j = 0; j < 128; ++j) {
      float wo = HS.b.Wo[k][jb + j];
      float4 wc = *(const float4*)&HS.b.Wc[jb + j][nb];
      a0 += wo * wc.x; a1 += wo * wc.y; a2 += wo * wc.z; a3 += wo * wc.w;
    }
    a0 += __shfl_xor(a0, 8); a1 += __shfl_xor(a1, 8);
    a2 += __shfl_xor(a2, 8); a3 += __shfl_xor(a3, 8);
    if (half == 0) {
      u16* dst = wt_f + (size_t)z * 65536;
      dst[(size_t)(n0 + nb + 0) * 256 + k0 + k] = f2bf(a0);
      dst[(size_t)(n0 + nb + 1) * 256 + k0 + k] = f2bf(a1);
      dst[(size_t)(n0 + nb + 2) * 256 + k0 + k] = f2bf(a2);
      dst[(size_t)(n0 + nb + 3) * 256 + k0 + k] = f2bf(a3);
    }
    if (k0 == 0 && tid < 32) {
      float b = 0.f;
      const float* bo = intra_b + 768;
      for (int j = 0; j < 256; ++j) b += bo[j] * HS.b.Wc[j][tid];
      bfq[z * 256 + n0 + tid] = b + cross_b[z * 256 + n0 + tid];
    }
  }
}

// ---- launch 2 (512 thr, 8 waves): gather + GEMM1 + LN + ReLU + GEMM2 (16 rows/block) ----
__global__ __launch_bounds__(512) void gemm12_fused(const float* __restrict__ feat_s,
                                                    const float* __restrict__ feat_t,
                                                    const int* __restrict__ idxb,
                                                    const u16* __restrict__ wt_h1,
                                                    const float* __restrict__ head_b1,
                                                    const u16* __restrict__ wt_h2,
                                                    const float* __restrict__ head_b2,
                                                    u16* __restrict__ bufB,
                                                    float* __restrict__ st2) {
  __shared__ u16 As[16][520];     // gathered input (K=512)
  __shared__ u16 Yb[16][264];     // layer-1 output (bf16), then LN+ReLU'd in place
  __shared__ u16 Bs[256][40];     // W1 staging chunks
  __shared__ float sums[16][16], sqs[16][16], mS[16], rS[16];
  int t = threadIdx.x, l = t & 63, w = t >> 6;   // 8 waves
  int m0 = blockIdx.x * 16;
  // gather: each thread loads one channel per row
#pragma unroll
  for (int row = 0; row < 16; ++row) {
    int grow = m0 + row;
    int bi = grow >> 7, n = grow & 127, b = bi & 7;
    const float* fp = (bi < 8) ? feat_s : feat_t;
    int pos = idxb[bi * NN + n];
    As[row][t] = f2bf(fp[(size_t)b * CENC * HW + (size_t)t * HW + pos]);
  }
  __syncthreads();
  // ---- GEMM1: Y = As @ W1t + b1 ----
  f32x4 acc[2];
  acc[0] = (f32x4){0.f, 0.f, 0.f, 0.f};
  acc[1] = (f32x4){0.f, 0.f, 0.f, 0.f};
  for (int kc = 0; kc < 16; ++kc) {
#pragma unroll
    for (int i = 0; i < 2; ++i) {
      int e = t + i * 512;
      int nn2 = e >> 2, ch8 = (e & 3) * 8;
      *(u32x4*)&Bs[nn2][ch8] = *(const u32x4*)&wt_h1[(size_t)nn2 * 512 + kc * 32 + ch8];
    }
    __syncthreads();
    u32x4 af = *(const u32x4*)&As[l & 15][kc * 32 + (l >> 4) * 8];
#pragma unroll
    for (int i = 0; i < 2; ++i) {
      u32x4 bf = *(const u32x4*)&Bs[w * 32 + i * 16 + (l & 15)][(l >> 4) * 8];
      mfma_b(acc[i], af, bf);
    }
    __syncthreads();
  }
  asm volatile("s_nop 7\n\ts_nop 7" ::);
  // epilogue -> Yb (LDS) + stats (LDS)
#pragma unroll
  for (int i = 0; i < 2; ++i) {
    int col = w * 32 + i * 16 + (l & 15);
    float bb = head_b1[col];
#pragma unroll
    for (int r = 0; r < 4; ++r) {
      int row = (l >> 4) * 4 + r;
      float o = acc[i][r] + bb;
      Yb[row][col] = f2bf(o);
      float s = o, q = o * o;
#pragma unroll
      for (int m = 1; m < 16; m <<= 1) { s += __shfl_xor(s, m); q += __shfl_xor(q, m); }
      if ((l & 15) == 0) {
        sums[row][w * 2 + i] = s;
        sqs[row][w * 2 + i]  = q;
      }
    }
  }
  __syncthreads();
  // LN params per row
  if (t < 16) {
    float s = 0.f, q = 0.f;
#pragma unroll
    for (int i = 0; i < 16; ++i) { s += sums[t][i]; q += sqs[t][i]; }
    float mm = s * (1.f / 256.f);
    mS[t] = mm;
    rS[t] = rsqrtf(fmaxf(q * (1.f / 256.f) - mm * mm, 0.f) + 1e-5f);
  }
  __syncthreads();
  // LN + ReLU transform in place (512 thr x 8 elems)
  {
    int row = t >> 5, c8 = (t & 31) * 8;
    u32x4 v = *(const u32x4*)&Yb[row][c8];
    float mm = mS[row], rr = rS[row];
#pragma unroll
    for (int j = 0; j < 4; ++j) {
      float f0 = fmaxf((bf2f(v[j] & 0xffffu) - mm) * rr, 0.f);
      float f1 = fmaxf((bf2f(v[j] >> 16) - mm) * rr, 0.f);
      v[j] = pack2(f0, f1);
    }
    __syncthreads();
    *(u32x4*)&Yb[row][c8] = v;
  }
  __syncthreads();
  // ---- GEMM2: bufB = Yb @ W2t + b2, stats -> st2 ; B streamed from L2 ----
#pragma unroll
  for (int i = 0; i < 2; ++i) {
    int n0 = (w * 2 + i) * 16;
    f32x4 a2 = {0.f, 0.f, 0.f, 0.f};
    int ar = l & 15;
    int bn = n0 + (l & 15);
#pragma unroll
    for (int ks = 0; ks < 8; ++ks) {
      int ak = ks * 32 + (l >> 4) * 8;
      u32x4 af = *(const u32x4*)&Yb[ar][ak];
      u32x4 bf = *(const u32x4*)&wt_h2[(size_t)bn * 256 + ak];
      mfma_b(a2, af, bf);
    }
    asm volatile("s_nop 7\n\ts_nop 7" ::);
    float bb = head_b2[n0 + (l & 15)];
#pragma unroll
    for (int r = 0; r < 4; ++r) {
      int row = m0 + (l >> 4) * 4 + r;
      float o = a2[r] + bb;
      bufB[(size_t)row * 256 + n0 + (l & 15)] = f2bf(o);
      float s = o, q = o * o;
#pragma unroll
      for (int m = 1; m < 16; m <<= 1) { s += __shfl_xor(s, m); q += __shfl_xor(q, m); }
      if ((l & 15) == 0) {
        st2[(size_t)row * 32 + w * 2 + i]      = s;
        st2[(size_t)row * 32 + 16 + w * 2 + i] = q;
      }
    }
  }
}

// ---------------- bf16 MFMA GEMM, 512 thr / 8 waves, full-K LDS stage ----------------
template<int K>
__global__ __launch_bounds__(512) void gemm_mf(const u16* __restrict__ A,
                                               const u16* __restrict__ Wt,
                                               const float* __restrict__ bias,
                                               u16* __restrict__ Cb,
                                               float* __restrict__ Cf,
                                               int ldc,
                                               const float* __restrict__ in_stats, int in_relu,
                                               float* __restrict__ out_stats) {
  constexpr int LDK = K + 8;
  constexpr int KC = K / 8;
  __shared__ u16 As[32][LDK];
  __shared__ u16 Bs[64][LDK];
  __shared__ float mS[32], rS[32];
  int n0 = blockIdx.x * 64, m0 = blockIdx.y * 32;
  int t = threadIdx.x;
  if (in_stats) {
    if (t < 32) {
      const float* sp = in_stats + (size_t)(m0 + t) * 32;
      float s = 0.f, q = 0.f;
#pragma unroll
      for (int i = 0; i < 16; ++i) { s += sp[i]; q += sp[16 + i]; }
      float mm = s * (1.f / 256.f);
      float var = q * (1.f / 256.f) - mm * mm;
      mS[t] = mm;
      rS[t] = rsqrtf(fmaxf(var, 0.f) + 1e-5f);
    }
    __syncthreads();
  }
  for (int i = t; i < 32 * KC; i += 512) {
    int row = i / KC, c8 = (i % KC) * 8;
    u32x4 av = *(const u32x4*)&A[(size_t)(m0 + row) * K + c8];
    if (in_stats) {
      float mm = mS[row], rr = rS[row];
#pragma unroll
      for (int j = 0; j < 4; ++j) {
        float f0 = (bf2f(av[j] & 0xffffu) - mm) * rr;
        float f1 = (bf2f(av[j] >> 16) - mm) * rr;
        if (in_relu) { f0 = fmaxf(f0, 0.f); f1 = fmaxf(f1, 0.f); }
        av[j] = pack2(f0, f1);
      }
    }
    *(u32x4*)&As[row][c8] = av;
  }
  for (int i = t; i < 64 * KC; i += 512) {
    int row = i / KC, c8 = (i % KC) * 8;
    *(u32x4*)&Bs[row][c8] = *(const u32x4*)&Wt[(size_t)(n0 + row) * K + c8];
  }
  __syncthreads();
  int l = t & 63, w = t >> 6;          // 8 waves
  int wr = w >> 2, wc = w & 3;         // 2x4 quadrants of 32x64
  int fra = wr * 16 + (l & 15);
  int frk = (l >> 4) * 8;
  int fb = wc * 16 + (l & 15);
  f32x4 acc = {0.f, 0.f, 0.f, 0.f};
#pragma unroll
  for (int ks = 0; ks < K / 32; ++ks) {
    u32x4 af = *(const u32x4*)&As[fra][ks * 32 + frk];
    u32x4 bf = *(const u32x4*)&Bs[fb][ks * 32 + frk];
    mfma_b(acc, af, bf);
  }
  asm volatile("s_nop 7\n\ts_nop 7" ::);
  int col0 = n0 + wc * 16 + (l & 15);
  int rbase = m0 + wr * 16 + (l >> 4) * 4;
  float b0 = bias ? bias[col0] : 0.f;
#pragma unroll
  for (int r = 0; r < 4; ++r) {
    int row = rbase + r;
    float o0 = acc[r] + b0;
    if (Cb) Cb[(size_t)row * 256 + col0] = f2bf(o0);
    if (Cf && row < ROWS1) Cf[(size_t)row * ldc + col0] = o0;
    if (out_stats) {
      float s0 = o0, q0 = o0 * o0;
#pragma unroll
      for (int m = 1; m < 16; m <<= 1) { s0 += __shfl_xor(s0, m); q0 += __shfl_xor(q0, m); }
      if ((l & 15) == 0) {
        int slot = (n0 >> 4) + wc;
        out_stats[(size_t)row * 32 + slot]      = s0;
        out_stats[(size_t)row * 32 + 16 + slot] = q0;
      }
    }
  }
}

// ---------------- fused QKV + attention: block = (slot, head), 128 blocks x 1024 thr ----------------
template<int HASLN, int SWAP>
__global__ __launch_bounds__(1024) void fattn_kernel(const u16* __restrict__ X,
                                                     const u16* __restrict__ Wt,
                                                     const float* __restrict__ bias,
                                                     const float* __restrict__ stats,
                                                     u16* __restrict__ O) {
  __shared__ u16 Qs[128][40];
  __shared__ u16 Ks[128][40];
  __shared__ u16 Vt[32][136];
  __shared__ float Sf[128][132];
  __shared__ u16 Pb[128][136];
  __shared__ float mS[128], rS[128], dn[128];
  int blk = blockIdx.x;
  int bb = blk >> 3, h = blk & 7;
  int kb = SWAP ? (bb ^ 8) : bb;
  int baseQ = bb * 128, baseKV = kb * 128;
  int t = threadIdx.x, l = t & 63, w = t >> 6;
  if (HASLN) {
    if (t < 128) {
      const float* sp = stats + (size_t)(baseQ + t) * 32;
      float s = 0.f, q = 0.f;
#pragma unroll
      for (int i = 0; i < 16; ++i) { s += sp[i]; q += sp[16 + i]; }
      float mm = s * (1.f / 256.f);
      mS[t] = mm;
      rS[t] = rsqrtf(fmaxf(q * (1.f / 256.f) - mm * mm, 0.f) + 1e-5f);
    }
    __syncthreads();
  }
  const float scale = 0.17677669529663687f;   // 1/sqrt(32)
  int mt = w >> 1, nt = w & 1;
  // ---- phase 1: Q/K/V head-slice gemms (M=128, N=32, K=256) ----
#pragma unroll
  for (int z = 0; z < 3; ++z) {
    const u16* Xz = X + (size_t)(z == 0 ? baseQ : baseKV) * 256;
    f32x4 acc = {0.f, 0.f, 0.f, 0.f};
    int ar = mt * 16 + (l & 15);
    int bn = h * 32 + nt * 16 + (l & 15);
#pragma unroll
    for (int ks = 0; ks < 8; ++ks) {
      int ak = ks * 32 + (l >> 4) * 8;
      u32x4 af = *(const u32x4*)&Xz[(size_t)ar * 256 + ak];
      if (HASLN) {
        float mm = mS[ar], rr = rS[ar];
#pragma unroll
        for (int j = 0; j < 4; ++j) {
          float f0 = (bf2f(af[j] & 0xffffu) - mm) * rr;
          float f1 = (bf2f(af[j] >> 16) - mm) * rr;
          af[j] = pack2(f0, f1);
        }
      }
      u32x4 bf = *(const u32x4*)&Wt[(size_t)z * 65536 + (size_t)bn * 256 + ak];
      mfma_s(acc, af, bf);
    }
    asm volatile("s_nop 7\n\ts_nop 7" ::);
    float bv = bias[z * 256 + h * 32 + nt * 16 + (l & 15)];
    int cn = nt * 16 + (l & 15);
#pragma unroll
    for (int r2 = 0; r2 < 4; ++r2) {
      int rr2 = mt * 16 + (l >> 4) * 4 + r2;
      float v = acc[r2] + bv;
      if (z == 0)      Qs[rr2][cn] = f2bf(v);
      else if (z == 1) Ks[rr2][cn] = f2bf(v);
      else             Vt[cn][rr2] = f2bf(v);
    }
  }
  __syncthreads();
  // ---- phase 2: S = Q @ K^T * scale (M=128, N=128, K=32) ----
#pragma unroll
  for (int i = 0; i < 4; ++i) {
    int tile = w * 4 + i, mt2 = tile >> 3, nt2 = tile & 7;
    f32x4 acc = {0.f, 0.f, 0.f, 0.f};
    u32x4 af = *(const u32x4*)&Qs[mt2 * 16 + (l & 15)][(l >> 4) * 8];
    u32x4 bf = *(const u32x4*)&Ks[nt2 * 16 + (l & 15)][(l >> 4) * 8];
    mfma_s(acc, af, bf);
    asm volatile("s_nop 7\n\ts_nop 7" ::);
#pragma unroll
    for (int r2 = 0; r2 < 4; ++r2)
      Sf[mt2 * 16 + (l >> 4) * 4 + r2][nt2 * 16 + (l & 15)] = acc[r2] * scale;
  }
  __syncthreads();
  // ---- phase 3: row softmax (row r: 8 threads x 16 cols) ----
  {
    int r = t >> 3, p = t & 7;
    int js = p * 16;
    float v[16];
#pragma unroll
    for (int q4 = 0; q4 < 4; ++q4) {
      float4 f = *(const float4*)&Sf[r][js + q4 * 4];
      v[q4 * 4 + 0] = f.x; v[q4 * 4 + 1] = f.y; v[q4 * 4 + 2] = f.z; v[q4 * 4 + 3] = f.w;
    }
    float mx = v[0];
#pragma unroll
    for (int j = 1; j < 16; ++j) mx = fmaxf(mx, v[j]);
    for (int m = 1; m < 8; m <<= 1) mx = fmaxf(mx, __shfl_xor(mx, m));
    float e[16];
    float den = 0.f;
#pragma unroll
    for (int j = 0; j < 16; ++j) { e[j] = __expf(v[j] - mx); den += e[j]; }
    for (int m = 1; m < 8; m <<= 1) den += __shfl_xor(den, m);
    unsigned* pw = (unsigned*)&Pb[r][js];
#pragma unroll
    for (int jp = 0; jp < 8; ++jp) pw[jp] = pack2(e[2 * jp], e[2 * jp + 1]);
    if (p == 0) dn[r] = 1.0f / den;
  }
  __syncthreads();
  // ---- phase 4: O = (P @ V^T) / den (M=128, N=32, K=128) ----
  {
    f32x4 acc = {0.f, 0.f, 0.f, 0.f};
#pragma unroll
    for (int ks = 0; ks < 4; ++ks) {
      u32x4 af = *(const u32x4*)&Pb[mt * 16 + (l & 15)][ks * 32 + (l >> 4) * 8];
      u32x4 bf = *(const u32x4*)&Vt[nt * 16 + (l & 15)][ks * 32 + (l >> 4) * 8];
      mfma_s(acc, af, bf);
    }
    asm volatile("s_nop 7\n\ts_nop 7" ::);
    int cn = nt * 16 + (l & 15);
#pragma unroll
    for (int r2 = 0; r2 < 4; ++r2) {
      int rr2 = mt * 16 + (l >> 4) * 4 + r2;
      O[(size_t)(baseQ + rr2) * 256 + h * 32 + cn] = f2bf(acc[r2] * dn[rr2]);
    }
  }
}

// ---------------- tail: 0..7 = aff+NT+sinkhorn+focal ; 8..519 = cls (4 rows each) ----------------
struct SkSmem {
  union { u16 tmpL[128][264]; float Km[128][133]; } u;
  float u_[NN];
  float v_[NN];
  float red[20];
};
struct ClsSmem {
  float xs[4][256];
  float part[4][128];
  float red[8];
};
union TailSmem { SkSmem sk; ClsSmem cls; };

__device__ __forceinline__ void ticket_finalize(float* acc, float* out) {
  __threadfence();
  int tk = atomicAdd((int*)acc + 3, 1);
  if (tk == TAILB - 1) {
    float a0 = atomicAdd(acc + 0, 0.0f);
    float a1 = atomicAdd(acc + 1, 0.0f);
    out[ROWS1 * DD] = a0 + 10.0f * a1;
  }
}

__global__ __launch_bounds__(1024) void tail_kernel(const u16* __restrict__ bufH,
                                                    const u16* __restrict__ wt_af,
                                                    const u16* __restrict__ w1t,
                                                    const float* __restrict__ b1,
                                                    const float* __restrict__ W2,
                                                    const float* __restrict__ b2,
                                                    float* __restrict__ acc,
                                                    float* __restrict__ out) {
  __shared__ TailSmem sm;
  int t = threadIdx.x;
  int bid = blockIdx.x;
  if (bid < 8) {
    int b = bid;
    int l = t & 63, w = t >> 6;
    int tr = w >> 1;
    const u16* c1 = bufH + (size_t)(b * 128) * 256;
    const u16* c2 = bufH + (size_t)(1024 + b * 128) * 256;
    {
      int tcB = (w & 1) * 8;
      f32x4 accA[8];
#pragma unroll
      for (int i = 0; i < 8; ++i) accA[i] = (f32x4){0.f, 0.f, 0.f, 0.f};
      for (int ks = 0; ks < 8; ++ks) {
        int kk = ks * 32 + (l >> 4) * 8;
        u32x4 af = *(const u32x4*)&c1[(size_t)(tr * 16 + (l & 15)) * 256 + kk];
#pragma unroll
        for (int i = 0; i < 8; ++i) {
          u32x4 bf = *(const u32x4*)&wt_af[(size_t)((tcB + i) * 16 + (l & 15)) * 256 + kk];
          mfma_b(accA[i], af, bf);
        }
      }
      asm volatile("s_nop 7\n\ts_nop 7" ::);
      int rb = tr * 16 + (l >> 4) * 4;
#pragma unroll
      for (int i = 0; i < 8; ++i) {
        int col = (tcB + i) * 16 + (l & 15);
#pragma unroll
        for (int r2 = 0; r2 < 4; ++r2)
          sm.sk.u.tmpL[rb + r2][col] = f2bf(accA[i][r2]);
      }
    }
    __syncthreads();
    f32x4 aB[4];
    {
      int tcB = (w & 1) * 4;
#pragma unroll
      for (int i = 0; i < 4; ++i) aB[i] = (f32x4){0.f, 0.f, 0.f, 0.f};
      for (int ks = 0; ks < 8; ++ks) {
        int kk = ks * 32 + (l >> 4) * 8;
        u32x4 a0 = *(const u32x4*)&sm.sk.u.tmpL[tr * 16 + (l & 15)][kk];
#pragma unroll
        for (int i = 0; i < 4; ++i) {
          u32x4 bf = *(const u32x4*)&c2[(size_t)((tcB + i) * 16 + (l & 15)) * 256 + kk];
          mfma_b(aB[i], a0, bf);
        }
      }
      asm volatile("s_nop 7\n\ts_nop 7" ::);
    }
    __syncthreads();   // all tmpL reads complete before aliased Km writes
    {
      int tcB = (w & 1) * 4;
      int rb = tr * 16 + (l >> 4) * 4;
#pragma unroll
      for (int i = 0; i < 4; ++i) {
        int col = (tcB + i) * 16 + (l & 15);
#pragma unroll
        for (int r2 = 0; r2 < 4; ++r2)
          sm.sk.u.Km[rb + r2][col] = aB[i][r2];
      }
    }
    __syncthreads();
    int r = t >> 3, cg = t & 7;
    int c = t >> 3, rg = t & 7;
    float kr[16], kc[16];
    {
#pragma unroll
      for (int q4 = 0; q4 < 4; ++q4) {
        float4 f = *(const float4*)&sm.sk.u.Km[r][cg * 16 + q4 * 4];
        kr[q4 * 4 + 0] = f.x; kr[q4 * 4 + 1] = f.y; kr[q4 * 4 + 2] = f.z; kr[q4 * 4 + 3] = f.w;
      }
#pragma unroll
      for (int q = 0; q < 16; ++q)
        kc[q] = sm.sk.u.Km[rg * 16 + q][c];
    }
    float s = 0.f;
#pragma unroll
    for (int q = 0; q < 16; ++q) s += kr[q];
    for (int m = 1; m < 64; m <<= 1) s += __shfl_xor(s, m);
    if ((t & 63) == 0) sm.sk.red[t >> 6] = s;
    __syncthreads();
    if (t == 0) { float tt = 0.f; for (int i = 0; i < 16; ++i) tt += sm.sk.red[i]; sm.sk.red[16] = tt; }
    __syncthreads();
    float mu = sm.sk.red[16] * (1.0f / 16384.f);
    __syncthreads();
    float sq = 0.f;
#pragma unroll
    for (int q = 0; q < 16; ++q) { float d = kr[q] - mu; sq += d * d; }
    for (int m = 1; m < 64; m <<= 1) sq += __shfl_xor(sq, m);
    if ((t & 63) == 0) sm.sk.red[t >> 6] = sq;
    __syncthreads();
    if (t == 0) { float tt = 0.f; for (int i = 0; i < 16; ++i) tt += sm.sk.red[i]; sm.sk.red[17] = tt; }
    __syncthreads();
    float inv = 1.0f / sqrtf(sm.sk.red[17] * (1.0f / 16384.f) + 1e-5f);
#pragma unroll
    for (int q = 0; q < 16; ++q) { kr[q] = (kr[q] - mu) * inv; kc[q] = (kc[q] - mu) * inv; }
    if (t < NN) { sm.sk.u_[t] = 0.f; sm.sk.v_[t] = 0.f; }
    __syncthreads();
    for (int iter = 0; iter < 10; ++iter) {
      float tmp[16];
      {
        const float4* vp = (const float4*)(sm.sk.v_ + cg * 16);
#pragma unroll
        for (int q4 = 0; q4 < 4; ++q4) {
          float4 f = vp[q4];
          tmp[q4 * 4 + 0] = kr[q4 * 4 + 0] - f.x; tmp[q4 * 4 + 1] = kr[q4 * 4 + 1] - f.y;
          tmp[q4 * 4 + 2] = kr[q4 * 4 + 2] - f.z; tmp[q4 * 4 + 3] = kr[q4 * 4 + 3] - f.w;
        }
        float mx = tmp[0];
#pragma unroll
        for (int q = 1; q < 16; ++q) mx = fmaxf(mx, tmp[q]);
        for (int m = 1; m < 8; m <<= 1) mx = fmaxf(mx, __shfl_xor(mx, m));
        float smv = 0.f;
#pragma unroll
        for (int q = 0; q < 16; ++q) smv += __expf(tmp[q] - mx);
        for (int m = 1; m < 8; m <<= 1) smv += __shfl_xor(smv, m);
        if (cg == 0) sm.sk.u_[r] = mx + __logf(smv);
      }
      __syncthreads();
      {
        const float4* up = (const float4*)(sm.sk.u_ + rg * 16);
#pragma unroll
        for (int q4 = 0; q4 < 4; ++q4) {
          float4 f = up[q4];
          tmp[q4 * 4 + 0] = kc[q4 * 4 + 0] - f.x; tmp[q4 * 4 + 1] = kc[q4 * 4 + 1] - f.y;
          tmp[q4 * 4 + 2] = kc[q4 * 4 + 2] - f.z; tmp[q4 * 4 + 3] = kc[q4 * 4 + 3] - f.w;
        }
        float mx = tmp[0];
#pragma unroll
        for (int q = 1; q < 16; ++q) mx = fmaxf(mx, tmp[q]);
        for (int m = 1; m < 8; m <<= 1) mx = fmaxf(mx, __shfl_xor(mx, m));
        float smv = 0.f;
#pragma unroll
        for (int q = 0; q < 16; ++q) smv += __expf(tmp[q] - mx);
        for (int m = 1; m < 8; m <<= 1) smv += __shfl_xor(smv, m);
        if (rg == 0) sm.sk.v_[c] = mx + __logf(smv);
      }
      __syncthreads();
    }
    float ur = sm.sk.u_[r];
    float fsum = 0.f;
    {
      const float4* vp = (const float4*)(sm.sk.v_ + cg * 16);
#pragma unroll
      for (int q4 = 0; q4 < 4; ++q4) {
        float4 f = vp[q4];
        float vv[4] = {f.x, f.y, f.z, f.w};
#pragma unroll
        for (int j = 0; j < 4; ++j) {
          float P = __expf(kr[q4 * 4 + j] - ur - vv[j]);
          float pt = fminf(fmaxf(P, 1e-6f), 1.0f - 1e-6f);
          int col = cg * 16 + q4 * 4 + j;
          bool gt = (r < 64) == (col < 64);
          float wgt = gt ? (-0.25f * (1.f - pt) * (1.f - pt)) : (-0.75f * pt * pt);
          float lg = gt ? __logf(pt) : __logf(1.f - pt);
          fsum += wgt * lg;
        }
      }
    }
    for (int m = 1; m < 64; m <<= 1) fsum += __shfl_xor(fsum, m);
    if ((t & 63) == 0) sm.sk.red[t >> 6] = fsum;
    __syncthreads();
    if (t == 0) {
      float tt = 0.f; for (int i = 0; i < 16; ++i) tt += sm.sk.red[i];
      atomicAdd(acc + 1, tt * (1.0f / 131072.f));
      ticket_finalize(acc, out);
    }
  } else {
    int row0 = (bid - 8) * 4;
    {
      int rr = t >> 8, cc = t & 255;
      sm.cls.xs[rr][cc] = bf2f(bufH[(size_t)(row0 + rr) * 256 + cc]);
    }
    __syncthreads();
    int grp = t >> 8, col = t & 127, kh = (t >> 7) & 1;
    const u16* wp = w1t + (size_t)col * 256 + kh * 128;
    const float* xp = &sm.cls.xs[grp][kh * 128];
    float h = 0.f;
#pragma unroll
    for (int i = 0; i < 16; ++i) {
      u32x4 wv = *(const u32x4*)&wp[i * 8];
      const float* x8 = xp + i * 8;
      h += x8[0] * bf2f(wv[0] & 0xffffu) + x8[1] * bf2f(wv[0] >> 16)
         + x8[2] * bf2f(wv[1] & 0xffffu) + x8[3] * bf2f(wv[1] >> 16)
         + x8[4] * bf2f(wv[2] & 0xffffu) + x8[5] * bf2f(wv[2] >> 16)
         + x8[6] * bf2f(wv[3] & 0xffffu) + x8[7] * bf2f(wv[3] >> 16);
    }
    if (kh == 1) sm.cls.part[grp][col] = h;
    __syncthreads();
    if (kh == 0) {
      float z = h + sm.cls.part[grp][col] + b1[col];
      float p = fmaxf(z, 0.f) * W2[col];
#pragma unroll
      for (int m = 1; m < 64; m <<= 1) p += __shfl_xor(p, m);
      if ((t & 63) == 0) sm.cls.red[grp * 2 + ((t >> 6) & 1)] = p;
    }
    __syncthreads();
    if (t == 0) {
      float total = 0.f;
      float bb2 = b2[0];
#pragma unroll
      for (int g = 0; g < 4; ++g) {
        float z = sm.cls.red[2 * g] + sm.cls.red[2 * g + 1] + bb2;
        float lab = (((row0 + g) & 127) < 64) ? 1.f : 0.f;
        total += fmaxf(z, 0.f) - z * lab + log1pf(__expf(-fabsf(z)));
      }
      atomicAdd(acc, total * (1.0f / 1024.0f));
      ticket_finalize(acc, out);
    }
  }
}

extern "C" void kernel_launch(void* const* d_in, const int* in_sizes, int n_in,
                              void* d_out, int out_size, void* d_ws, size_t ws_size,
                              hipStream_t stream) {
  const float* feat_s  = (const float*)d_in[0];
  const float* score_s = (const float*)d_in[1];
  const float* feat_t  = (const float*)d_in[2];
  const float* score_t = (const float*)d_in[3];
  const float* head_W1 = (const float*)d_in[4];
  const float* head_b1 = (const float*)d_in[5];
  const float* head_W2 = (const float*)d_in[6];
  const float* head_b2 = (const float*)d_in[7];
  const float* intra_W = (const float*)d_in[8];
  const float* intra_b = (const float*)d_in[9];
  const float* cross_W = (const float*)d_in[10];
  const float* cross_b = (const float*)d_in[11];
  const float* cls_W1  = (const float*)d_in[12];
  const float* cls_b1  = (const float*)d_in[13];
  const float* cls_W2  = (const float*)d_in[14];
  const float* cls_b2  = (const float*)d_in[15];
  const float* aff_A   = (const float*)d_in[16];

  u16* bufB  = (u16*)d_ws;                       // 2048*256
  u16* bufH  = bufB + ROWS2 * DD;
  u16* attnb = bufH + ROWS2 * DD;                // intra attn out
  u16* atto2 = attnb + ROWS2 * DD;               // cross attn out
  u16* wt    = atto2 + ROWS2 * DD;               // 786432
  u16* w1t   = wt + 786432;                      // 32768
  u16* wt_f  = w1t + 32768;                      // 3*65536 fused cross weights
  float* st2 = (float*)(wt_f + 3 * 65536);       // 2048*32
  float* bfq = st2 + ROWS2 * 32;                 // 768 fused cross biases
  float* acc = bfq + 768;                        // loss0, loss1, pad, ticket
  int* idxb  = (int*)(acc + 8);                  // 2048 ints
  float* out_f = (float*)d_out;

  u16* wt_h1 = wt;
  u16* wt_h2 = wt + 131072;
  u16* wt_in = wt_h2 + 65536;
  u16* wt_cr = wt_in + 4 * 65536;
  u16* wt_af = wt_cr + 4 * 65536;

  head_kernel<<<1024, 512, 0, stream>>>(score_s, score_t, idxb, acc,
                                        head_W1, head_W2, intra_W, cross_W, aff_A, cls_W1,
                                        intra_b, cross_b, wt, w1t, wt_f, bfq);
  // gather + head-MLP layer1 + LN + ReLU + layer2 (one launch)
  gemm12_fused<<<128, 512, 0, stream>>>(feat_s, feat_t, idxb, wt_h1, head_b1,
                                        wt_h2, head_b2, bufB, st2);

  dim3 g1(4, 64, 1);
  const float* nulf = nullptr;
  float* nulw = nullptr;

  // fused intra QKV + attention (LN on load), one block per (slot, head)
  fattn_kernel<1, 0><<<128, 1024, 0, stream>>>(bufB, wt_in, intra_b, st2, attnb);
  // fused cross QKV (folded intra out-proj weights) + attention
  fattn_kernel<0, 1><<<128, 1024, 0, stream>>>(attnb, wt_f, bfq, nulf, atto2);
  // C = attn @ Wo_cross + bo (+ n1 -> d_out)
  gemm_mf<256><<<g1, 512, 0, stream>>>(atto2, wt_cr + 3 * 65536, cross_b + 768, bufH, out_f,
                                       256, nulf, 0, nulw);
  tail_kernel<<<TAILB, 1024, 0, stream>>>(bufH, wt_af, w1t, cls_b1, cls_W2, cls_b2,
                                          acc, out_f);
}

// Round 17
// 195.683 us; speedup vs baseline: 1.0621x; 1.0621x over previous
//
#include <hip/hip_runtime.h>
#include <math.h>

#define BIMG 8
#define HW 9216
#define CENC 512
#define NN 128
#define DD 256
#define NHEAD 8
#define DH 32
#define ROWS1 1024
#define ROWS2 2048
#define TAILB 520   // 8 sinkhorn + 512 cls blocks

typedef unsigned long long ull;
typedef unsigned short u16;
typedef __attribute__((ext_vector_type(4))) float f32x4;
typedef __attribute__((ext_vector_type(4))) unsigned u32x4;
typedef __attribute__((ext_vector_type(2))) unsigned u32x2;

__device__ __forceinline__ u16 f2bf(float f) {
  unsigned u = __float_as_uint(f);
  u += 0x7fffu + ((u >> 16) & 1u);
  return (u16)(u >> 16);
}
__device__ __forceinline__ float bf2f(unsigned h) { return __uint_as_float(h << 16); }
__device__ __forceinline__ unsigned pack2(float a, float b) {
  return (unsigned)f2bf(a) | ((unsigned)f2bf(b) << 16);
}
__device__ __forceinline__ void mfma_b(f32x4& acc, u32x4 a, u32x4 b) {
  asm volatile("v_mfma_f32_16x16x32_bf16 %0, %1, %2, %0" : "+v"(acc) : "v"(a), "v"(b));
}
// safe variant: s_nop covers VALU-write -> MFMA-read hazard (invisible to compiler in asm)
__device__ __forceinline__ void mfma_s(f32x4& acc, u32x4 a, u32x4 b) {
  asm volatile("s_nop 1\n\tv_mfma_f32_16x16x32_bf16 %0, %1, %2, %0" : "+v"(acc) : "v"(a), "v"(b));
}

__device__ __forceinline__ ull cmpex_keep(ull k, ull o, bool keepMax) {
  return ((k > o) == keepMax) ? k : o;
}
__device__ __forceinline__ void bsort64(ull& k, int lane) {
#pragma unroll
  for (int size = 2; size <= 64; size <<= 1) {
#pragma unroll
    for (int stride = size >> 1; stride > 0; stride >>= 1) {
      ull o = __shfl_xor(k, stride);
      bool keepMax = (((lane & size) == 0) == ((lane & stride) == 0));
      k = cmpex_keep(k, o, keepMax);
    }
  }
}
__device__ __forceinline__ void bmerge64(ull& top, ull b, int lane) {
  ull rev = __shfl_xor(b, 63);
  ull m = top > rev ? top : rev;
#pragma unroll
  for (int stride = 32; stride > 0; stride >>= 1) {
    ull o = __shfl_xor(m, stride);
    m = cmpex_keep(m, o, (lane & stride) == 0);
  }
  top = m;
}
__device__ __forceinline__ ull lds_merge(ull a, ull brev, int lane) {
  ull m = a > brev ? a : brev;
#pragma unroll
  for (int stride = 32; stride > 0; stride >>= 1) {
    ull o = __shfl_xor(m, stride);
    m = cmpex_keep(m, o, (lane & stride) == 0);
  }
  return m;
}

// ---- launch 1 (512 thr): 0..31 top-64 ; 32..799 W transpose ; 800..831 cls_W1 ;
//                          832..1023 fused cross weights ----
__global__ __launch_bounds__(512) void head_kernel(const float* __restrict__ score_s,
                                                   const float* __restrict__ score_t,
                                                   int* __restrict__ idx_out,
                                                   float* __restrict__ loss_acc,
                                                   const float* __restrict__ hw1,
                                                   const float* __restrict__ hw2,
                                                   const float* __restrict__ iw,
                                                   const float* __restrict__ cw,
                                                   const float* __restrict__ aw,
                                                   const float* __restrict__ clsW1,
                                                   const float* __restrict__ intra_b,
                                                   const float* __restrict__ cross_b,
                                                   u16* __restrict__ wt,
                                                   u16* __restrict__ w1t,
                                                   u16* __restrict__ wt_f,
                                                   float* __restrict__ bfq) {
  __shared__ union {
    struct { ull sm[512]; float tile[32][33]; } a;
    struct { float Wo[32][264]; float Wc[256][40]; } b;
  } HS;
  int tid = threadIdx.x;
  if (blockIdx.x < 32) {
    int blk = blockIdx.x;
    int bi = blk >> 1, neg = blk & 1;
    int lane = tid & 63, w = tid >> 6;
    if (blk == 0 && tid < 4) loss_acc[tid] = 0.f;   // loss0, loss1, pad, ticket
    const float* sp = (bi < 8 ? score_s : score_t) + (size_t)(bi & 7) * HW;
    int q0 = w * 18;
    ull keys[18];
#pragma unroll
    for (int j = 0; j < 18; ++j) {
      float x = sp[(q0 + j) * 64 + lane];
      unsigned ub = __float_as_uint(x);
      unsigned u = (ub & 0x80000000u) ? ~ub : (ub | 0x80000000u);
      if (neg) u = ~u;
      int gi = (q0 + j) * 64 + lane;
      keys[j] = ((ull)u << 32) | (unsigned)(~gi);
    }
    ull top1 = keys[0]; bsort64(top1, lane);
    ull top2 = keys[9]; bsort64(top2, lane);
#pragma unroll
    for (int j = 1; j < 9; ++j) {
      ull k1 = keys[j], k2 = keys[9 + j];
      bsort64(k1, lane);
      bsort64(k2, lane);
      bmerge64(top1, k1, lane);
      bmerge64(top2, k2, lane);
    }
    bmerge64(top1, top2, lane);
    HS.a.sm[w * 64 + lane] = top1;
    __syncthreads();
    if (w < 4) {
      ull m = lds_merge(HS.a.sm[(2 * w) * 64 + lane],
                        HS.a.sm[(2 * w + 1) * 64 + (63 - lane)], lane);
      HS.a.sm[(2 * w) * 64 + lane] = m;
    }
    __syncthreads();
    if (w < 2) {
      ull m = lds_merge(HS.a.sm[(4 * w) * 64 + lane],
                        HS.a.sm[(4 * w + 2) * 64 + (63 - lane)], lane);
      HS.a.sm[(4 * w) * 64 + lane] = m;
    }
    __syncthreads();
    if (w == 0) {
      ull m = lds_merge(HS.a.sm[lane], HS.a.sm[4 * 64 + (63 - lane)], lane);
      idx_out[bi * NN + neg * 64 + lane] = (int)(~(unsigned)(m & 0xffffffffull));
    }
  } else if (blockIdx.x < 800) {
    int bid = blockIdx.x - 32;
    const float* src; u16* dst; int K, k0, n0;
    if (bid < 128) {
      src = hw1; dst = wt; K = 512;
      k0 = (bid >> 3) * 32; n0 = (bid & 7) * 32;
    } else {
      int id2 = bid - 128;
      int m = id2 >> 6, tt = id2 & 63;
      K = 256;
      k0 = (tt >> 3) * 32; n0 = (tt & 7) * 32;
      src = (m == 0) ? hw2 : (m < 5) ? iw + (size_t)(m - 1) * 65536
          : (m < 9) ? cw + (size_t)(m - 5) * 65536 : aw;
      dst = wt + 131072 + (size_t)m * 65536;
    }
    int r = tid >> 3, c = (tid & 7) * 4;
    if (tid < 256) {
      float4 v = *(const float4*)&src[(size_t)(k0 + r) * 256 + n0 + c];
      HS.a.tile[r][c] = v.x; HS.a.tile[r][c + 1] = v.y;
      HS.a.tile[r][c + 2] = v.z; HS.a.tile[r][c + 3] = v.w;
    }
    __syncthreads();
    if (tid < 256) {
      u32x2 o;
      o[0] = pack2(HS.a.tile[c][r], HS.a.tile[c + 1][r]);
      o[1] = pack2(HS.a.tile[c + 2][r], HS.a.tile[c + 3][r]);
      *(u32x2*)&dst[(size_t)(n0 + r) * K + k0 + c] = o;
    }
  } else if (blockIdx.x < 832) {
    int bid3 = blockIdx.x - 800;     // cls_W1 [256][128] -> bf16 [128][256]
    int k0 = (bid3 >> 2) * 32, n0 = (bid3 & 3) * 32;
    int r = tid >> 3, c = (tid & 7) * 4;
    if (tid < 256) {
      float4 v = *(const float4*)&clsW1[(size_t)(k0 + r) * 128 + n0 + c];
      HS.a.tile[r][c] = v.x; HS.a.tile[r][c + 1] = v.y;
      HS.a.tile[r][c + 2] = v.z; HS.a.tile[r][c + 3] = v.w;
    }
    __syncthreads();
    if (tid < 256) {
      u32x2 o;
      o[0] = pack2(HS.a.tile[c][r], HS.a.tile[c + 1][r]);
      o[1] = pack2(HS.a.tile[c + 2][r], HS.a.tile[c + 3][r]);
      *(u32x2*)&w1t[(size_t)(n0 + r) * 256 + k0 + c] = o;
    }
  } else {
    // fused cross weights: W'[z](k,n) = sum_j Wo_i[k][j]*Wc[z][j][n] (fp32) -> bf16 [n][k]
    int bid4 = blockIdx.x - 832;       // 0..191
    int z = bid4 >> 6, tt = bid4 & 63;
    int k0 = (tt >> 3) * 32, n0 = (tt & 7) * 32;
    const float* Wo = iw + 3 * 65536;
    const float* Wc = cw + (size_t)z * 65536;
    for (int e = tid; e < 2048; e += 512) {
      int row = e >> 6, c4 = (e & 63) * 4;
      *(float4*)&HS.b.Wo[row][c4] = *(const float4*)&Wo[(size_t)(k0 + row) * 256 + c4];
    }
    for (int e = tid; e < 2048; e += 512) {
      int row = e >> 3, c4 = (e & 7) * 4;
      *(float4*)&HS.b.Wc[row][c4] = *(const float4*)&Wc[(size_t)row * 256 + n0 + c4];
    }
    __syncthreads();
    int k = tid >> 4, half = (tid >> 3) & 1, nb = (tid & 7) * 4;
    float a0 = 0.f, a1 = 0.f, a2 = 0.f, a3 = 0.f;
    int jb = half * 128;
#pragma unroll 8
    for (int j = 0; j < 128; ++j) {
      float wo = HS.b.Wo[k][jb + j];
      float4 wc = *(const float4*)&HS.b.Wc[jb + j][nb];
      a0 += wo * wc.x; a1 += wo * wc.y; a2 += wo * wc.z; a3 += wo * wc.w;
    }
    a0 += __shfl_xor(a0, 8); a1 += __shfl_xor(a1, 8);
    a2 += __shfl_xor(a2, 8); a3 += __shfl_xor(a3, 8);
    if (half == 0) {
      u16* dst = wt_f + (size_t)z * 65536;
      dst[(size_t)(n0 + nb + 0) * 256 + k0 + k] = f2bf(a0);
      dst[(size_t)(n0 + nb + 1) * 256 + k0 + k] = f2bf(a1);
      dst[(size_t)(n0 + nb + 2) * 256 + k0 + k] = f2bf(a2);
      dst[(size_t)(n0 + nb + 3) * 256 + k0 + k] = f2bf(a3);
    }
    if (k0 == 0 && tid < 32) {
      float b = 0.f;
      const float* bo = intra_b + 768;
      for (int j = 0; j < 256; ++j) b += bo[j] * HS.b.Wc[j][tid];
      bfq[z * 256 + n0 + tid] = b + cross_b[z * 256 + n0 + tid];
    }
  }
}

// ---- launch 2 (512 thr, 8 waves): gather + GEMM1 + LN + ReLU + GEMM2 (16 rows/block) ----
__global__ __launch_bounds__(512) void gemm12_fused(const float* __restrict__ feat_s,
                                                    const float* __restrict__ feat_t,
                                                    const int* __restrict__ idxb,
                                                    const u16* __restrict__ wt_h1,
                                                    const float* __restrict__ head_b1,
                                                    const u16* __restrict__ wt_h2,
                                                    const float* __restrict__ head_b2,
                                                    u16* __restrict__ bufB,
                                                    float* __restrict__ st2) {
  __shared__ u16 As[16][520];     // gathered input (K=512)
  __shared__ u16 Yb[16][264];     // layer-1 output (bf16), then LN+ReLU'd in place
  __shared__ u16 Bs[256][40];     // W1 staging chunks
  __shared__ float sums[16][16], sqs[16][16], mS[16], rS[16];
  int t = threadIdx.x, l = t & 63, w = t >> 6;   // 8 waves
  int m0 = blockIdx.x * 16;
#pragma unroll
  for (int row = 0; row < 16; ++row) {
    int grow = m0 + row;
    int bi = grow >> 7, n = grow & 127, b = bi & 7;
    const float* fp = (bi < 8) ? feat_s : feat_t;
    int pos = idxb[bi * NN + n];
    As[row][t] = f2bf(fp[(size_t)b * CENC * HW + (size_t)t * HW + pos]);
  }
  __syncthreads();
  // ---- GEMM1: Y = As @ W1t + b1 ----
  f32x4 acc[2];
  acc[0] = (f32x4){0.f, 0.f, 0.f, 0.f};
  acc[1] = (f32x4){0.f, 0.f, 0.f, 0.f};
  for (int kc = 0; kc < 16; ++kc) {
#pragma unroll
    for (int i = 0; i < 2; ++i) {
      int e = t + i * 512;
      int nn2 = e >> 2, ch8 = (e & 3) * 8;
      *(u32x4*)&Bs[nn2][ch8] = *(const u32x4*)&wt_h1[(size_t)nn2 * 512 + kc * 32 + ch8];
    }
    __syncthreads();
    u32x4 af = *(const u32x4*)&As[l & 15][kc * 32 + (l >> 4) * 8];
#pragma unroll
    for (int i = 0; i < 2; ++i) {
      u32x4 bf = *(const u32x4*)&Bs[w * 32 + i * 16 + (l & 15)][(l >> 4) * 8];
      mfma_b(acc[i], af, bf);
    }
    __syncthreads();
  }
  asm volatile("s_nop 7\n\ts_nop 7" ::);
#pragma unroll
  for (int i = 0; i < 2; ++i) {
    int col = w * 32 + i * 16 + (l & 15);
    float bb = head_b1[col];
#pragma unroll
    for (int r = 0; r < 4; ++r) {
      int row = (l >> 4) * 4 + r;
      float o = acc[i][r] + bb;
      Yb[row][col] = f2bf(o);
      float s = o, q = o * o;
#pragma unroll
      for (int m = 1; m < 16; m <<= 1) { s += __shfl_xor(s, m); q += __shfl_xor(q, m); }
      if ((l & 15) == 0) {
        sums[row][w * 2 + i] = s;
        sqs[row][w * 2 + i]  = q;
      }
    }
  }
  __syncthreads();
  if (t < 16) {
    float s = 0.f, q = 0.f;
#pragma unroll
    for (int i = 0; i < 16; ++i) { s += sums[t][i]; q += sqs[t][i]; }
    float mm = s * (1.f / 256.f);
    mS[t] = mm;
    rS[t] = rsqrtf(fmaxf(q * (1.f / 256.f) - mm * mm, 0.f) + 1e-5f);
  }
  __syncthreads();
  {
    int row = t >> 5, c8 = (t & 31) * 8;
    u32x4 v = *(const u32x4*)&Yb[row][c8];
    float mm = mS[row], rr = rS[row];
#pragma unroll
    for (int j = 0; j < 4; ++j) {
      float f0 = fmaxf((bf2f(v[j] & 0xffffu) - mm) * rr, 0.f);
      float f1 = fmaxf((bf2f(v[j] >> 16) - mm) * rr, 0.f);
      v[j] = pack2(f0, f1);
    }
    __syncthreads();
    *(u32x4*)&Yb[row][c8] = v;
  }
  __syncthreads();
#pragma unroll
  for (int i = 0; i < 2; ++i) {
    int n0 = (w * 2 + i) * 16;
    f32x4 a2 = {0.f, 0.f, 0.f, 0.f};
    int ar = l & 15;
    int bn = n0 + (l & 15);
#pragma unroll
    for (int ks = 0; ks < 8; ++ks) {
      int ak = ks * 32 + (l >> 4) * 8;
      u32x4 af = *(const u32x4*)&Yb[ar][ak];
      u32x4 bf = *(const u32x4*)&wt_h2[(size_t)bn * 256 + ak];
      mfma_b(a2, af, bf);
    }
    asm volatile("s_nop 7\n\ts_nop 7" ::);
    float bb = head_b2[n0 + (l & 15)];
#pragma unroll
    for (int r = 0; r < 4; ++r) {
      int row = m0 + (l >> 4) * 4 + r;
      float o = a2[r] + bb;
      bufB[(size_t)row * 256 + n0 + (l & 15)] = f2bf(o);
      float s = o, q = o * o;
#pragma unroll
      for (int m = 1; m < 16; m <<= 1) { s += __shfl_xor(s, m); q += __shfl_xor(q, m); }
      if ((l & 15) == 0) {
        st2[(size_t)row * 32 + w * 2 + i]      = s;
        st2[(size_t)row * 32 + 16 + w * 2 + i] = q;
      }
    }
  }
}

// ---------------- bf16 MFMA GEMM, 512 thr / 8 waves, full-K LDS stage ----------------
template<int K>
__global__ __launch_bounds__(512) void gemm_mf(const u16* __restrict__ A,
                                               const u16* __restrict__ Wt,
                                               const float* __restrict__ bias,
                                               u16* __restrict__ Cb,
                                               float* __restrict__ Cf,
                                               int ldc,
                                               const float* __restrict__ in_stats, int in_relu,
                                               float* __restrict__ out_stats) {
  constexpr int LDK = K + 8;
  constexpr int KC = K / 8;
  __shared__ u16 As[32][LDK];
  __shared__ u16 Bs[64][LDK];
  __shared__ float mS[32], rS[32];
  int n0 = blockIdx.x * 64, m0 = blockIdx.y * 32;
  int t = threadIdx.x;
  if (in_stats) {
    if (t < 32) {
      const float* sp = in_stats + (size_t)(m0 + t) * 32;
      float s = 0.f, q = 0.f;
#pragma unroll
      for (int i = 0; i < 16; ++i) { s += sp[i]; q += sp[16 + i]; }
      float mm = s * (1.f / 256.f);
      float var = q * (1.f / 256.f) - mm * mm;
      mS[t] = mm;
      rS[t] = rsqrtf(fmaxf(var, 0.f) + 1e-5f);
    }
    __syncthreads();
  }
  for (int i = t; i < 32 * KC; i += 512) {
    int row = i / KC, c8 = (i % KC) * 8;
    u32x4 av = *(const u32x4*)&A[(size_t)(m0 + row) * K + c8];
    if (in_stats) {
      float mm = mS[row], rr = rS[row];
#pragma unroll
      for (int j = 0; j < 4; ++j) {
        float f0 = (bf2f(av[j] & 0xffffu) - mm) * rr;
        float f1 = (bf2f(av[j] >> 16) - mm) * rr;
        if (in_relu) { f0 = fmaxf(f0, 0.f); f1 = fmaxf(f1, 0.f); }
        av[j] = pack2(f0, f1);
      }
    }
    *(u32x4*)&As[row][c8] = av;
  }
  for (int i = t; i < 64 * KC; i += 512) {
    int row = i / KC, c8 = (i % KC) * 8;
    *(u32x4*)&Bs[row][c8] = *(const u32x4*)&Wt[(size_t)(n0 + row) * K + c8];
  }
  __syncthreads();
  int l = t & 63, w = t >> 6;          // 8 waves
  int wr = w >> 2, wc = w & 3;         // 2x4 quadrants of 32x64
  int fra = wr * 16 + (l & 15);
  int frk = (l >> 4) * 8;
  int fb = wc * 16 + (l & 15);
  f32x4 acc = {0.f, 0.f, 0.f, 0.f};
#pragma unroll
  for (int ks = 0; ks < K / 32; ++ks) {
    u32x4 af = *(const u32x4*)&As[fra][ks * 32 + frk];
    u32x4 bf = *(const u32x4*)&Bs[fb][ks * 32 + frk];
    mfma_b(acc, af, bf);
  }
  asm volatile("s_nop 7\n\ts_nop 7" ::);
  int col0 = n0 + wc * 16 + (l & 15);
  int rbase = m0 + wr * 16 + (l >> 4) * 4;
  float b0 = bias ? bias[col0] : 0.f;
#pragma unroll
  for (int r = 0; r < 4; ++r) {
    int row = rbase + r;
    float o0 = acc[r] + b0;
    if (Cb) Cb[(size_t)row * 256 + col0] = f2bf(o0);
    if (Cf && row < ROWS1) Cf[(size_t)row * ldc + col0] = o0;
    if (out_stats) {
      float s0 = o0, q0 = o0 * o0;
#pragma unroll
      for (int m = 1; m < 16; m <<= 1) { s0 += __shfl_xor(s0, m); q0 += __shfl_xor(q0, m); }
      if ((l & 15) == 0) {
        int slot = (n0 >> 4) + wc;
        out_stats[(size_t)row * 32 + slot]      = s0;
        out_stats[(size_t)row * 32 + 16 + slot] = q0;
      }
    }
  }
}

// ---- fused QKV + attention: block = (slot, head, q-half), 256 blocks x 512 thr ----
// 64 Q-rows per block; K/V (128 rows) recomputed per q-half (cheap) ; ~75 KB LDS -> 2 blocks/CU
template<int HASLN, int SWAP>
__global__ __launch_bounds__(512) void fattn_kernel(const u16* __restrict__ X,
                                                    const u16* __restrict__ Wt,
                                                    const float* __restrict__ bias,
                                                    const float* __restrict__ stats,
                                                    u16* __restrict__ O) {
  __shared__ u16 Qs[64][40];
  __shared__ u16 Ks[128][40];
  __shared__ u16 Vt[32][136];
  __shared__ float Sf[64][132];
  __shared__ u16 Pb[64][136];
  __shared__ float mS[128], rS[128], dn[64];
  int blk = blockIdx.x;
  int bb = blk >> 4, h = (blk >> 1) & 7, qh = blk & 1;
  int kb = SWAP ? (bb ^ 8) : bb;
  int baseQ = bb * 128 + qh * 64, baseKV = kb * 128;
  int t = threadIdx.x, l = t & 63, w = t >> 6;   // 8 waves
  if (HASLN) {
    if (t < 128) {
      const float* sp = stats + (size_t)(kb * 128 + t) * 32;   // kb==bb for HASLN path
      float s = 0.f, q = 0.f;
#pragma unroll
      for (int i = 0; i < 16; ++i) { s += sp[i]; q += sp[16 + i]; }
      float mm = s * (1.f / 256.f);
      mS[t] = mm;
      rS[t] = rsqrtf(fmaxf(q * (1.f / 256.f) - mm * mm, 0.f) + 1e-5f);
    }
    __syncthreads();
  }
  const float scale = 0.17677669529663687f;   // 1/sqrt(32)
  int mt = w >> 1, nt = w & 1;                 // 4x2 tiles of 64x32
  // ---- phase 1a: Q head-slice gemm (M=64, N=32, K=256) ----
  {
    f32x4 acc = {0.f, 0.f, 0.f, 0.f};
    int ar = mt * 16 + (l & 15);
    int bn = h * 32 + nt * 16 + (l & 15);
#pragma unroll
    for (int ks = 0; ks < 8; ++ks) {
      int ak = ks * 32 + (l >> 4) * 8;
      u32x4 af = *(const u32x4*)&X[(size_t)(baseQ + ar) * 256 + ak];
      if (HASLN) {
        float mm = mS[qh * 64 + ar], rr = rS[qh * 64 + ar];
#pragma unroll
        for (int j = 0; j < 4; ++j) {
          float f0 = (bf2f(af[j] & 0xffffu) - mm) * rr;
          float f1 = (bf2f(af[j] >> 16) - mm) * rr;
          af[j] = pack2(f0, f1);
        }
      }
      u32x4 bf = *(const u32x4*)&Wt[(size_t)bn * 256 + ak];
      mfma_s(acc, af, bf);
    }
    asm volatile("s_nop 7\n\ts_nop 7" ::);
    float bv = bias[h * 32 + nt * 16 + (l & 15)];
    int cn = nt * 16 + (l & 15);
#pragma unroll
    for (int r2 = 0; r2 < 4; ++r2)
      Qs[mt * 16 + (l >> 4) * 4 + r2][cn] = f2bf(acc[r2] + bv);
  }
  // ---- phase 1b: K, V head-slice gemms (M=128 in two 64-halves) ----
#pragma unroll
  for (int z = 1; z < 3; ++z) {
#pragma unroll
    for (int kv = 0; kv < 2; ++kv) {
      f32x4 acc = {0.f, 0.f, 0.f, 0.f};
      int ar = mt * 16 + (l & 15);
      int bn = h * 32 + nt * 16 + (l & 15);
#pragma unroll
      for (int ks = 0; ks < 8; ++ks) {
        int ak = ks * 32 + (l >> 4) * 8;
        u32x4 af = *(const u32x4*)&X[(size_t)(baseKV + kv * 64 + ar) * 256 + ak];
        if (HASLN) {
          float mm = mS[kv * 64 + ar], rr = rS[kv * 64 + ar];
#pragma unroll
          for (int j = 0; j < 4; ++j) {
            float f0 = (bf2f(af[j] & 0xffffu) - mm) * rr;
            float f1 = (bf2f(af[j] >> 16) - mm) * rr;
            af[j] = pack2(f0, f1);
          }
        }
        u32x4 bf = *(const u32x4*)&Wt[(size_t)z * 65536 + (size_t)bn * 256 + ak];
        mfma_s(acc, af, bf);
      }
      asm volatile("s_nop 7\n\ts_nop 7" ::);
      float bv = bias[z * 256 + h * 32 + nt * 16 + (l & 15)];
      int cn = nt * 16 + (l & 15);
#pragma unroll
      for (int r2 = 0; r2 < 4; ++r2) {
        int rr2 = kv * 64 + mt * 16 + (l >> 4) * 4 + r2;
        float v = acc[r2] + bv;
        if (z == 1) Ks[rr2][cn] = f2bf(v);
        else        Vt[cn][rr2] = f2bf(v);
      }
    }
  }
  __syncthreads();
  // ---- phase 2: S = Q @ K^T * scale (M=64, N=128, K=32) : 32 tiles, 4/wave ----
#pragma unroll
  for (int i = 0; i < 4; ++i) {
    int tile = w * 4 + i, mt2 = tile >> 3, nt2 = tile & 7;
    f32x4 acc = {0.f, 0.f, 0.f, 0.f};
    u32x4 af = *(const u32x4*)&Qs[mt2 * 16 + (l & 15)][(l >> 4) * 8];
    u32x4 bf = *(const u32x4*)&Ks[nt2 * 16 + (l & 15)][(l >> 4) * 8];
    mfma_s(acc, af, bf);
    asm volatile("s_nop 7\n\ts_nop 7" ::);
#pragma unroll
    for (int r2 = 0; r2 < 4; ++r2)
      Sf[mt2 * 16 + (l >> 4) * 4 + r2][nt2 * 16 + (l & 15)] = acc[r2] * scale;
  }
  __syncthreads();
  // ---- phase 3: row softmax (row r: 8 threads x 16 cols) ----
  {
    int r = t >> 3, p = t & 7;
    int js = p * 16;
    float v[16];
#pragma unroll
    for (int q4 = 0; q4 < 4; ++q4) {
      float4 f = *(const float4*)&Sf[r][js + q4 * 4];
      v[q4 * 4 + 0] = f.x; v[q4 * 4 + 1] = f.y; v[q4 * 4 + 2] = f.z; v[q4 * 4 + 3] = f.w;
    }
    float mx = v[0];
#pragma unroll
    for (int j = 1; j < 16; ++j) mx = fmaxf(mx, v[j]);
    for (int m = 1; m < 8; m <<= 1) mx = fmaxf(mx, __shfl_xor(mx, m));
    float e[16];
    float den = 0.f;
#pragma unroll
    for (int j = 0; j < 16; ++j) { e[j] = __expf(v[j] - mx); den += e[j]; }
    for (int m = 1; m < 8; m <<= 1) den += __shfl_xor(den, m);
    unsigned* pw = (unsigned*)&Pb[r][js];
#pragma unroll
    for (int jp = 0; jp < 8; ++jp) pw[jp] = pack2(e[2 * jp], e[2 * jp + 1]);
    if (p == 0) dn[r] = 1.0f / den;
  }
  __syncthreads();
  // ---- phase 4: O = (P @ V^T) / den (M=64, N=32, K=128) : 8 tiles, 1/wave ----
  {
    f32x4 acc = {0.f, 0.f, 0.f, 0.f};
#pragma unroll
    for (int ks = 0; ks < 4; ++ks) {
      u32x4 af = *(const u32x4*)&Pb[mt * 16 + (l & 15)][ks * 32 + (l >> 4) * 8];
      u32x4 bf = *(const u32x4*)&Vt[nt * 16 + (l & 15)][ks * 32 + (l >> 4) * 8];
      mfma_s(acc, af, bf);
    }
    asm volatile("s_nop 7\n\ts_nop 7" ::);
    int cn = nt * 16 + (l & 15);
#pragma unroll
    for (int r2 = 0; r2 < 4; ++r2) {
      int rr2 = mt * 16 + (l >> 4) * 4 + r2;
      O[(size_t)(baseQ + rr2) * 256 + h * 32 + cn] = f2bf(acc[r2] * dn[rr2]);
    }
  }
}

// ---------------- tail: 0..7 = aff+NT+sinkhorn+focal ; 8..519 = cls (4 rows each) ----------------
struct SkSmem {
  union { u16 tmpL[128][264]; float Km[128][133]; } u;
  float u_[NN];
  float v_[NN];
  float red[20];
};
struct ClsSmem {
  float xs[4][256];
  float part[4][128];
  float red[8];
};
union TailSmem { SkSmem sk; ClsSmem cls; };

__device__ __forceinline__ void ticket_finalize(float* acc, float* out) {
  __threadfence();
  int tk = atomicAdd((int*)acc + 3, 1);
  if (tk == TAILB - 1) {
    float a0 = atomicAdd(acc + 0, 0.0f);
    float a1 = atomicAdd(acc + 1, 0.0f);
    out[ROWS1 * DD] = a0 + 10.0f * a1;
  }
}

__global__ __launch_bounds__(1024) void tail_kernel(const u16* __restrict__ bufH,
                                                    const u16* __restrict__ wt_af,
                                                    const u16* __restrict__ w1t,
                                                    const float* __restrict__ b1,
                                                    const float* __restrict__ W2,
                                                    const float* __restrict__ b2,
                                                    float* __restrict__ acc,
                                                    float* __restrict__ out) {
  __shared__ TailSmem sm;
  int t = threadIdx.x;
  int bid = blockIdx.x;
  if (bid < 8) {
    int b = bid;
    int l = t & 63, w = t >> 6;
    int tr = w >> 1;
    const u16* c1 = bufH + (size_t)(b * 128) * 256;
    const u16* c2 = bufH + (size_t)(1024 + b * 128) * 256;
    {
      int tcB = (w & 1) * 8;
      f32x4 accA[8];
#pragma unroll
      for (int i = 0; i < 8; ++i) accA[i] = (f32x4){0.f, 0.f, 0.f, 0.f};
      for (int ks = 0; ks < 8; ++ks) {
        int kk = ks * 32 + (l >> 4) * 8;
        u32x4 af = *(const u32x4*)&c1[(size_t)(tr * 16 + (l & 15)) * 256 + kk];
#pragma unroll
        for (int i = 0; i < 8; ++i) {
          u32x4 bf = *(const u32x4*)&wt_af[(size_t)((tcB + i) * 16 + (l & 15)) * 256 + kk];
          mfma_b(accA[i], af, bf);
        }
      }
      asm volatile("s_nop 7\n\ts_nop 7" ::);
      int rb = tr * 16 + (l >> 4) * 4;
#pragma unroll
      for (int i = 0; i < 8; ++i) {
        int col = (tcB + i) * 16 + (l & 15);
#pragma unroll
        for (int r2 = 0; r2 < 4; ++r2)
          sm.sk.u.tmpL[rb + r2][col] = f2bf(accA[i][r2]);
      }
    }
    __syncthreads();
    f32x4 aB[4];
    {
      int tcB = (w & 1) * 4;
#pragma unroll
      for (int i = 0; i < 4; ++i) aB[i] = (f32x4){0.f, 0.f, 0.f, 0.f};
      for (int ks = 0; ks < 8; ++ks) {
        int kk = ks * 32 + (l >> 4) * 8;
        u32x4 a0 = *(const u32x4*)&sm.sk.u.tmpL[tr * 16 + (l & 15)][kk];
#pragma unroll
        for (int i = 0; i < 4; ++i) {
          u32x4 bf = *(const u32x4*)&c2[(size_t)((tcB + i) * 16 + (l & 15)) * 256 + kk];
          mfma_b(aB[i], a0, bf);
        }
      }
      asm volatile("s_nop 7\n\ts_nop 7" ::);
    }
    __syncthreads();   // all tmpL reads complete before aliased Km writes
    {
      int tcB = (w & 1) * 4;
      int rb = tr * 16 + (l >> 4) * 4;
#pragma unroll
      for (int i = 0; i < 4; ++i) {
        int col = (tcB + i) * 16 + (l & 15);
#pragma unroll
        for (int r2 = 0; r2 < 4; ++r2)
          sm.sk.u.Km[rb + r2][col] = aB[i][r2];
      }
    }
    __syncthreads();
    int r = t >> 3, cg = t & 7;
    int c = t >> 3, rg = t & 7;
    float kr[16], kc[16];
    {
#pragma unroll
      for (int q4 = 0; q4 < 4; ++q4) {
        float4 f = *(const float4*)&sm.sk.u.Km[r][cg * 16 + q4 * 4];
        kr[q4 * 4 + 0] = f.x; kr[q4 * 4 + 1] = f.y; kr[q4 * 4 + 2] = f.z; kr[q4 * 4 + 3] = f.w;
      }
#pragma unroll
      for (int q = 0; q < 16; ++q)
        kc[q] = sm.sk.u.Km[rg * 16 + q][c];
    }
    float s = 0.f;
#pragma unroll
    for (int q = 0; q < 16; ++q) s += kr[q];
    for (int m = 1; m < 64; m <<= 1) s += __shfl_xor(s, m);
    if ((t & 63) == 0) sm.sk.red[t >> 6] = s;
    __syncthreads();
    if (t == 0) { float tt = 0.f; for (int i = 0; i < 16; ++i) tt += sm.sk.red[i]; sm.sk.red[16] = tt; }
    __syncthreads();
    float mu = sm.sk.red[16] * (1.0f / 16384.f);
    __syncthreads();
    float sq = 0.f;
#pragma unroll
    for (int q = 0; q < 16; ++q) { float d = kr[q] - mu; sq += d * d; }
    for (int m = 1; m < 64; m <<= 1) sq += __shfl_xor(sq, m);
    if ((t & 63) == 0) sm.sk.red[t >> 6] = sq;
    __syncthreads();
    if (t == 0) { float tt = 0.f; for (int i = 0; i < 16; ++i) tt += sm.sk.red[i]; sm.sk.red[17] = tt; }
    __syncthreads();
    float inv = 1.0f / sqrtf(sm.sk.red[17] * (1.0f / 16384.f) + 1e-5f);
#pragma unroll
    for (int q = 0; q < 16; ++q) { kr[q] = (kr[q] - mu) * inv; kc[q] = (kc[q] - mu) * inv; }
    if (t < NN) { sm.sk.u_[t] = 0.f; sm.sk.v_[t] = 0.f; }
    __syncthreads();
    for (int iter = 0; iter < 10; ++iter) {
      float tmp[16];
      {
        const float4* vp = (const float4*)(sm.sk.v_ + cg * 16);
#pragma unroll
        for (int q4 = 0; q4 < 4; ++q4) {
          float4 f = vp[q4];
          tmp[q4 * 4 + 0] = kr[q4 * 4 + 0] - f.x; tmp[q4 * 4 + 1] = kr[q4 * 4 + 1] - f.y;
          tmp[q4 * 4 + 2] = kr[q4 * 4 + 2] - f.z; tmp[q4 * 4 + 3] = kr[q4 * 4 + 3] - f.w;
        }
        float mx = tmp[0];
#pragma unroll
        for (int q = 1; q < 16; ++q) mx = fmaxf(mx, tmp[q]);
        for (int m = 1; m < 8; m <<= 1) mx = fmaxf(mx, __shfl_xor(mx, m));
        float smv = 0.f;
#pragma unroll
        for (int q = 0; q < 16; ++q) smv += __expf(tmp[q] - mx);
        for (int m = 1; m < 8; m <<= 1) smv += __shfl_xor(smv, m);
        if (cg == 0) sm.sk.u_[r] = mx + __logf(smv);
      }
      __syncthreads();
      {
        const float4* up = (const float4*)(sm.sk.u_ + rg * 16);
#pragma unroll
        for (int q4 = 0; q4 < 4; ++q4) {
          float4 f = up[q4];
          tmp[q4 * 4 + 0] = kc[q4 * 4 + 0] - f.x; tmp[q4 * 4 + 1] = kc[q4 * 4 + 1] - f.y;
          tmp[q4 * 4 + 2] = kc[q4 * 4 + 2] - f.z; tmp[q4 * 4 + 3] = kc[q4 * 4 + 3] - f.w;
        }
        float mx = tmp[0];
#pragma unroll
        for (int q = 1; q < 16; ++q) mx = fmaxf(mx, tmp[q]);
        for (int m = 1; m < 8; m <<= 1) mx = fmaxf(mx, __shfl_xor(mx, m));
        float smv = 0.f;
#pragma unroll
        for (int q = 0; q < 16; ++q) smv += __expf(tmp[q] - mx);
        for (int m = 1; m < 8; m <<= 1) smv += __shfl_xor(smv, m);
        if (rg == 0) sm.sk.v_[c] = mx + __logf(smv);
      }
      __syncthreads();
    }
    float ur = sm.sk.u_[r];
    float fsum = 0.f;
    {
      const float4* vp = (const float4*)(sm.sk.v_ + cg * 16);
#pragma unroll
      for (int q4 = 0; q4 < 4; ++q4) {
        float4 f = vp[q4];
        float vv[4] = {f.x, f.y, f.z, f.w};
#pragma unroll
        for (int j = 0; j < 4; ++j) {
          float P = __expf(kr[q4 * 4 + j] - ur - vv[j]);
          float pt = fminf(fmaxf(P, 1e-6f), 1.0f - 1e-6f);
          int col = cg * 16 + q4 * 4 + j;
          bool gt = (r < 64) == (col < 64);
          float wgt = gt ? (-0.25f * (1.f - pt) * (1.f - pt)) : (-0.75f * pt * pt);
          float lg = gt ? __logf(pt) : __logf(1.f - pt);
          fsum += wgt * lg;
        }
      }
    }
    for (int m = 1; m < 64; m <<= 1) fsum += __shfl_xor(fsum, m);
    if ((t & 63) == 0) sm.sk.red[t >> 6] = fsum;
    __syncthreads();
    if (t == 0) {
      float tt = 0.f; for (int i = 0; i < 16; ++i) tt += sm.sk.red[i];
      atomicAdd(acc + 1, tt * (1.0f / 131072.f));
      ticket_finalize(acc, out);
    }
  } else {
    int row0 = (bid - 8) * 4;
    {
      int rr = t >> 8, cc = t & 255;
      sm.cls.xs[rr][cc] = bf2f(bufH[(size_t)(row0 + rr) * 256 + cc]);
    }
    __syncthreads();
    int grp = t >> 8, col = t & 127, kh = (t >> 7) & 1;
    const u16* wp = w1t + (size_t)col * 256 + kh * 128;
    const float* xp = &sm.cls.xs[grp][kh * 128];
    float h = 0.f;
#pragma unroll
    for (int i = 0; i < 16; ++i) {
      u32x4 wv = *(const u32x4*)&wp[i * 8];
      const float* x8 = xp + i * 8;
      h += x8[0] * bf2f(wv[0] & 0xffffu) + x8[1] * bf2f(wv[0] >> 16)
         + x8[2] * bf2f(wv[1] & 0xffffu) + x8[3] * bf2f(wv[1] >> 16)
         + x8[4] * bf2f(wv[2] & 0xffffu) + x8[5] * bf2f(wv[2] >> 16)
         + x8[6] * bf2f(wv[3] & 0xffffu) + x8[7] * bf2f(wv[3] >> 16);
    }
    if (kh == 1) sm.cls.part[grp][col] = h;
    __syncthreads();
    if (kh == 0) {
      float z = h + sm.cls.part[grp][col] + b1[col];
      float p = fmaxf(z, 0.f) * W2[col];
#pragma unroll
      for (int m = 1; m < 64; m <<= 1) p += __shfl_xor(p, m);
      if ((t & 63) == 0) sm.cls.red[grp * 2 + ((t >> 6) & 1)] = p;
    }
    __syncthreads();
    if (t == 0) {
      float total = 0.f;
      float bb2 = b2[0];
#pragma unroll
      for (int g = 0; g < 4; ++g) {
        float z = sm.cls.red[2 * g] + sm.cls.red[2 * g + 1] + bb2;
        float lab = (((row0 + g) & 127) < 64) ? 1.f : 0.f;
        total += fmaxf(z, 0.f) - z * lab + log1pf(__expf(-fabsf(z)));
      }
      atomicAdd(acc, total * (1.0f / 1024.0f));
      ticket_finalize(acc, out);
    }
  }
}

extern "C" void kernel_launch(void* const* d_in, const int* in_sizes, int n_in,
                              void* d_out, int out_size, void* d_ws, size_t ws_size,
                              hipStream_t stream) {
  const float* feat_s  = (const float*)d_in[0];
  const float* score_s = (const float*)d_in[1];
  const float* feat_t  = (const float*)d_in[2];
  const float* score_t = (const float*)d_in[3];
  const float* head_W1 = (const float*)d_in[4];
  const float* head_b1 = (const float*)d_in[5];
  const float* head_W2 = (const float*)d_in[6];
  const float* head_b2 = (const float*)d_in[7];
  const float* intra_W = (const float*)d_in[8];
  const float* intra_b = (const float*)d_in[9];
  const float* cross_W = (const float*)d_in[10];
  const float* cross_b = (const float*)d_in[11];
  const float* cls_W1  = (const float*)d_in[12];
  const float* cls_b1  = (const float*)d_in[13];
  const float* cls_W2  = (const float*)d_in[14];
  const float* cls_b2  = (const float*)d_in[15];
  const float* aff_A   = (const float*)d_in[16];

  u16* bufB  = (u16*)d_ws;                       // 2048*256
  u16* bufH  = bufB + ROWS2 * DD;
  u16* attnb = bufH + ROWS2 * DD;                // intra attn out
  u16* atto2 = attnb + ROWS2 * DD;               // cross attn out
  u16* wt    = atto2 + ROWS2 * DD;               // 786432
  u16* w1t   = wt + 786432;                      // 32768
  u16* wt_f  = w1t + 32768;                      // 3*65536 fused cross weights
  float* st2 = (float*)(wt_f + 3 * 65536);       // 2048*32
  float* bfq = st2 + ROWS2 * 32;                 // 768 fused cross biases
  float* acc = bfq + 768;                        // loss0, loss1, pad, ticket
  int* idxb  = (int*)(acc + 8);                  // 2048 ints
  float* out_f = (float*)d_out;

  u16* wt_h1 = wt;
  u16* wt_h2 = wt + 131072;
  u16* wt_in = wt_h2 + 65536;
  u16* wt_cr = wt_in + 4 * 65536;
  u16* wt_af = wt_cr + 4 * 65536;

  head_kernel<<<1024, 512, 0, stream>>>(score_s, score_t, idxb, acc,
                                        head_W1, head_W2, intra_W, cross_W, aff_A, cls_W1,
                                        intra_b, cross_b, wt, w1t, wt_f, bfq);
  // gather + head-MLP layer1 + LN + ReLU + layer2 (one launch)
  gemm12_fused<<<128, 512, 0, stream>>>(feat_s, feat_t, idxb, wt_h1, head_b1,
                                        wt_h2, head_b2, bufB, st2);

  dim3 g1(4, 64, 1);
  const float* nulf = nullptr;
  float* nulw = nullptr;

  // fused intra QKV + attention (LN on load), block = (slot, head, q-half)
  fattn_kernel<1, 0><<<256, 512, 0, stream>>>(bufB, wt_in, intra_b, st2, attnb);
  // fused cross QKV (folded intra out-proj weights) + attention
  fattn_kernel<0, 1><<<256, 512, 0, stream>>>(attnb, wt_f, bfq, nulf, atto2);
  // C = attn @ Wo_cross + bo (+ n1 -> d_out)
  gemm_mf<256><<<g1, 512, 0, stream>>>(atto2, wt_cr + 3 * 65536, cross_b + 768, bufH, out_f,
                                       256, nulf, 0, nulw);
  tail_kernel<<<TAILB, 1024, 0, stream>>>(bufH, wt_af, w1t, cls_b1, cls_W2, cls_b2,
                                          acc, out_f);
}